// Round 1
// baseline (4288.629 us; speedup 1.0000x reference)
//
#include <hip/hip_runtime.h>
#include <hip/hip_bf16.h>
#include <math.h>

#define N_DOC 4
#define C_    1024
#define D_    768
#define H_    12
#define E_    40
#define M_    3
#define P_    800
#define NP_   3200
#define EMB_  768
#define NREL_ 97
#define IN2_  1536   // 2*D

// ---------------------------------------------------------------- A: ent_emb
// ent_emb[n,e,d] = logsumexp_m seq[n, mpos[n,e,m]+1, d]   (fp64 math)
__global__ void k_ent_emb(const float* __restrict__ seq, const int* __restrict__ mpos,
                          float* __restrict__ ent_emb) {
  int ne = blockIdx.x;                 // 0..159
  int n = ne / E_, e = ne % E_;
  int base = (n * E_ + e) * M_;
  int p0 = mpos[base + 0] + 1, p1 = mpos[base + 1] + 1, p2 = mpos[base + 2] + 1;
  const float* s0 = seq + ((size_t)n * C_ + p0) * D_;
  const float* s1 = seq + ((size_t)n * C_ + p1) * D_;
  const float* s2 = seq + ((size_t)n * C_ + p2) * D_;
  float* out = ent_emb + (size_t)ne * D_;
  for (int d = threadIdx.x; d < D_; d += blockDim.x) {
    double a = s0[d], b = s1[d], c = s2[d];
    double mx = fmax(a, fmax(b, c));
    double s = exp(a - mx) + exp(b - mx) + exp(c - mx);
    out[d] = (float)(mx + log(s));
  }
}

// ---------------------------------------------------------------- B: ent_att
// ent_att[n,e,h,c] = mean_m att[n, h, mpos[n,e,m]+1, c]
__global__ void k_ent_att(const float* __restrict__ att, const int* __restrict__ mpos,
                          float* __restrict__ ent_att) {
  int idx = blockIdx.x * 256 + threadIdx.x;        // exactly N*E*H*C = 1966080
  int c = idx & (C_ - 1);
  int h = (idx >> 10) % H_;
  int rem = idx / (C_ * H_);
  int e = rem % E_;
  int n = rem / E_;
  int base = (n * E_ + e) * M_;
  float acc = 0.f;
#pragma unroll
  for (int m = 0; m < M_; ++m) {
    int p = mpos[base + m] + 1;
    acc += att[(((size_t)n * H_ + h) * C_ + p) * C_ + c];
  }
  ent_att[idx] = acc / 3.0f;
}

// ---------------------------------------------------------------- C: ht_att
// ht[np,c] = normalize_c( mean_h ea[n,hi,h,c]*ea[n,ti,h,c] )
__global__ void k_ht_att(const float* __restrict__ ent_att, const int* __restrict__ hts,
                         float* __restrict__ ht) {
  int np = blockIdx.x;                 // 0..3199
  int n = np / P_;
  int hi = hts[np * 2 + 0], ti = hts[np * 2 + 1];
  const float* ea_h = ent_att + (size_t)(n * E_ + hi) * H_ * C_;
  const float* ea_t = ent_att + (size_t)(n * E_ + ti) * H_ * C_;
  float v[4];
  float local = 0.f;
#pragma unroll
  for (int i = 0; i < 4; ++i) {
    int c = threadIdx.x + 256 * i;
    float a = 0.f;
#pragma unroll
    for (int h = 0; h < H_; ++h)
      a += ea_h[h * C_ + c] * ea_t[h * C_ + c];
    a /= 12.0f;
    v[i] = a;
    local += a;
  }
  __shared__ float red[256];
  red[threadIdx.x] = local;
  __syncthreads();
  for (int s = 128; s > 0; s >>= 1) {
    if (threadIdx.x < s) red[threadIdx.x] += red[threadIdx.x + s];
    __syncthreads();
  }
  float S = red[0] + 1e-5f;
#pragma unroll
  for (int i = 0; i < 4; ++i) {
    int c = threadIdx.x + 256 * i;
    ht[(size_t)np * C_ + c] = v[i] / S;
  }
}

// ---------------------------------------------------------------- D: rs GEMM
// rs[p_,o] = sum_c ht[p_,c] * seq[n,c,o]   (fp32 mul, chunked fp64 accum)
__global__ void k_rs(const float* __restrict__ ht, const float* __restrict__ seq,
                     float* __restrict__ rs) {
  const int pt0 = blockIdx.x * 16;     // 200 tiles, never crosses doc (800%16==0)
  const int n = pt0 / P_;
  const int ot = threadIdx.x & 63;
  const int jt = threadIdx.x >> 6;     // 0..3
  const int o0 = blockIdx.y * 256 + ot;
  __shared__ float hlds[16 * 66];
  float a32[4][4];
  double a64[4][4];
#pragma unroll
  for (int q = 0; q < 4; ++q)
#pragma unroll
    for (int i = 0; i < 4; ++i) { a32[q][i] = 0.f; a64[q][i] = 0.0; }
  const float* seqn = seq + (size_t)n * C_ * D_;
  for (int c0 = 0; c0 < C_; c0 += 64) {
    for (int l = threadIdx.x; l < 1024; l += 256) {
      int j = l >> 6, cc = l & 63;
      hlds[j * 66 + cc] = ht[(size_t)(pt0 + j) * C_ + c0 + cc];
    }
    __syncthreads();
#pragma unroll 4
    for (int cc = 0; cc < 64; ++cc) {
      float sv[4];
#pragma unroll
      for (int i = 0; i < 4; ++i) sv[i] = seqn[(size_t)(c0 + cc) * D_ + o0 + 64 * i];
#pragma unroll
      for (int q = 0; q < 4; ++q) {
        float w = hlds[(jt * 4 + q) * 66 + cc];
#pragma unroll
        for (int i = 0; i < 4; ++i) a32[q][i] += w * sv[i];
      }
    }
#pragma unroll
    for (int q = 0; q < 4; ++q)
#pragma unroll
      for (int i = 0; i < 4; ++i) { a64[q][i] += (double)a32[q][i]; a32[q][i] = 0.f; }
    __syncthreads();
  }
#pragma unroll
  for (int q = 0; q < 4; ++q) {
    int p = pt0 + jt * 4 + q;
#pragma unroll
    for (int i = 0; i < 4; ++i)
      rs[(size_t)p * D_ + o0 + 64 * i] = (float)a64[q][i];
  }
}

// ---------------------------------------------------------------- E: zh / zt
// out[p_,o] = tanh^(1or2)( sum_k X[p_,k]*W[k,o] + bias[o] ),  X = [gathered ent_emb | rs]
__global__ void k_zht(const float* __restrict__ ent_emb, const float* __restrict__ rs,
                      const int* __restrict__ hts, const float* __restrict__ W,
                      const float* __restrict__ bias, float* __restrict__ out,
                      int which, int dbl_tanh) {
  const int pt0 = blockIdx.x * 16;
  const int n = pt0 / P_;
  const int ot = threadIdx.x & 63;
  const int jt = threadIdx.x >> 6;
  const int o0 = blockIdx.y * 256 + ot;
  __shared__ float xlds[16 * 66];
  __shared__ int sidx[16];
  if (threadIdx.x < 16) sidx[threadIdx.x] = hts[(pt0 + threadIdx.x) * 2 + which];
  float a32[4][4];
  double a64[4][4];
#pragma unroll
  for (int q = 0; q < 4; ++q)
#pragma unroll
    for (int i = 0; i < 4; ++i) { a32[q][i] = 0.f; a64[q][i] = 0.0; }
  __syncthreads();
  for (int k0 = 0; k0 < IN2_; k0 += 64) {
    for (int l = threadIdx.x; l < 1024; l += 256) {
      int j = l >> 6, q = l & 63;
      int kx = k0 + q;
      float val;
      if (kx < D_) val = ent_emb[(size_t)(n * E_ + sidx[j]) * D_ + kx];
      else         val = rs[(size_t)(pt0 + j) * D_ + (kx - D_)];
      xlds[j * 66 + q] = val;
    }
    __syncthreads();
#pragma unroll 4
    for (int q = 0; q < 64; ++q) {
      float wv[4];
#pragma unroll
      for (int i = 0; i < 4; ++i) wv[i] = W[(size_t)(k0 + q) * EMB_ + o0 + 64 * i];
#pragma unroll
      for (int j = 0; j < 4; ++j) {
        float x = xlds[(jt * 4 + j) * 66 + q];
#pragma unroll
        for (int i = 0; i < 4; ++i) a32[j][i] += x * wv[i];
      }
    }
#pragma unroll
    for (int j = 0; j < 4; ++j)
#pragma unroll
      for (int i = 0; i < 4; ++i) { a64[j][i] += (double)a32[j][i]; a32[j][i] = 0.f; }
    __syncthreads();
  }
#pragma unroll
  for (int j = 0; j < 4; ++j) {
    int p = pt0 + jt * 4 + j;
#pragma unroll
    for (int i = 0; i < 4; ++i) {
      int o = o0 + 64 * i;
      double z = a64[j][i] + (double)bias[o];
      z = tanh(z);
      if (dbl_tanh) z = tanh(z);
      out[(size_t)p * EMB_ + o] = (float)z;
    }
  }
}

// ---------------------------------------------------------------- F: logits partial
// part[kg][p,r] = sum over k in kg-group of sum_{b,c} zh[p,64k+b]*zt[p,64k+c]*Wb[(64k+b)*64+c, r]
__global__ __launch_bounds__(128) void k_logits_part(
    const float* __restrict__ zh, const float* __restrict__ zt,
    const float* __restrict__ Wb, double* __restrict__ part) {
  const int pt0 = blockIdx.x * 32;     // 100 tiles
  const int kg = blockIdx.y;           // 0..3 -> k = kg*3 + kk
  const int rt = threadIdx.x & 15;     // r = rt + 16*i (i<6), plus r=96 on rt==0
  const int jg = threadIdx.x >> 4;     // 0..7 -> pairs jg*4+q
  __shared__ float zh_t[32 * 66];
  __shared__ float zt_t[32 * 66];
  float a32[4][7];
  double a64[4][7];
#pragma unroll
  for (int q = 0; q < 4; ++q)
#pragma unroll
    for (int i = 0; i < 7; ++i) { a32[q][i] = 0.f; a64[q][i] = 0.0; }
  for (int kk = 0; kk < 3; ++kk) {
    int k = kg * 3 + kk;
    __syncthreads();
    for (int l = threadIdx.x; l < 2048; l += 128) {
      int j = l >> 6, c = l & 63;
      zh_t[j * 66 + c] = zh[(size_t)(pt0 + j) * EMB_ + k * 64 + c];
      zt_t[j * 66 + c] = zt[(size_t)(pt0 + j) * EMB_ + k * 64 + c];
    }
    __syncthreads();
    for (int b = 0; b < 64; ++b) {
      float zhv[4];
#pragma unroll
      for (int q = 0; q < 4; ++q) zhv[q] = zh_t[(jg * 4 + q) * 66 + b];
      const float* wrow = Wb + (size_t)((k * 64 + b) * 64) * NREL_;
#pragma unroll 2
      for (int c = 0; c < 64; ++c) {
        float w[6];
#pragma unroll
        for (int i = 0; i < 6; ++i) w[i] = wrow[c * NREL_ + rt + 16 * i];
        float w6 = (rt == 0) ? wrow[c * NREL_ + 96] : 0.f;
#pragma unroll
        for (int q = 0; q < 4; ++q) {
          float pz = zhv[q] * zt_t[(jg * 4 + q) * 66 + c];
#pragma unroll
          for (int i = 0; i < 6; ++i) a32[q][i] += pz * w[i];
          a32[q][6] += pz * w6;
        }
      }
#pragma unroll
      for (int q = 0; q < 4; ++q)
#pragma unroll
        for (int i = 0; i < 7; ++i) { a64[q][i] += (double)a32[q][i]; a32[q][i] = 0.f; }
    }
  }
  double* po = part + (size_t)kg * NP_ * NREL_;
#pragma unroll
  for (int q = 0; q < 4; ++q) {
    int p = pt0 + jg * 4 + q;
#pragma unroll
    for (int i = 0; i < 6; ++i)
      po[(size_t)p * NREL_ + rt + 16 * i] = a64[q][i];
    if (rt == 0) po[(size_t)p * NREL_ + 96] = a64[q][6];
  }
}

// ---------------------------------------------------------------- G: finalize
// logits = sum_kg part + bb ; preds = (logits > logits[:,0]); preds[:,0] = (sum==0)
__global__ void k_final(const double* __restrict__ part, const float* __restrict__ bb,
                        float* __restrict__ out) {
  const int p = blockIdx.x;
  const int r = threadIdx.x;           // 128 threads
  __shared__ double th_s;
  __shared__ int cnt[128];
  double v = 0.0;
  if (r < NREL_) {
#pragma unroll
    for (int kg = 0; kg < 4; ++kg)
      v += part[(size_t)kg * NP_ * NREL_ + (size_t)p * NREL_ + r];
    v += (double)bb[r];
    out[(size_t)p * NREL_ + r] = (float)v;
  }
  if (r == 0) th_s = v;
  __syncthreads();
  int pred = (r >= 1 && r < NREL_ && v > th_s) ? 1 : 0;
  cnt[r] = pred;
  __syncthreads();
  for (int s = 64; s > 0; s >>= 1) {
    if (r < s) cnt[r] += cnt[r + s];
    __syncthreads();
  }
  if (r < NREL_) {
    float pv = (r == 0) ? ((cnt[0] == 0) ? 1.f : 0.f) : (float)pred;
    out[(size_t)NP_ * NREL_ + (size_t)p * NREL_ + r] = pv;
  }
}

extern "C" void kernel_launch(void* const* d_in, const int* in_sizes, int n_in,
                              void* d_out, int out_size, void* d_ws, size_t ws_size,
                              hipStream_t stream) {
  const float* seq  = (const float*)d_in[0];
  const float* att  = (const float*)d_in[1];
  const int*   mpos = (const int*)d_in[2];
  const int*   hts  = (const int*)d_in[3];
  const float* Wh   = (const float*)d_in[4];
  const float* bh   = (const float*)d_in[5];
  const float* Wt   = (const float*)d_in[6];
  const float* bt   = (const float*)d_in[7];
  const float* Wb   = (const float*)d_in[8];
  const float* bb   = (const float*)d_in[9];
  float* out = (float*)d_out;
  float* ws = (float*)d_ws;

  float* ent_emb = ws;                   // 122880
  float* ent_att = ws + 122880;          // 1966080
  float* ht      = ws + 2088960;         // 3276800
  float* rs      = ws + 5365760;         // 2457600
  float* zh      = ws + 7823360;         // 2457600
  float* zt      = ws + 10280960;        // 2457600
  double* part   = (double*)(ws + 12738560); // 4*3200*97 doubles (8B-aligned)

  k_ent_emb<<<160, 256, 0, stream>>>(seq, mpos, ent_emb);
  k_ent_att<<<7680, 256, 0, stream>>>(att, mpos, ent_att);
  k_ht_att<<<3200, 256, 0, stream>>>(ent_att, hts, ht);
  k_rs<<<dim3(200, 3), 256, 0, stream>>>(ht, seq, rs);
  k_zht<<<dim3(200, 3), 256, 0, stream>>>(ent_emb, rs, hts, Wh, bh, zh, 0, 1);
  k_zht<<<dim3(200, 3), 256, 0, stream>>>(ent_emb, rs, hts, Wt, bt, zt, 1, 0);
  k_logits_part<<<dim3(100, 4), 128, 0, stream>>>(zh, zt, Wb, part);
  k_final<<<3200, 128, 0, stream>>>(part, bb, out);
}

// Round 2
// 1446.740 us; speedup vs baseline: 2.9643x; 2.9643x over previous
//
#include <hip/hip_runtime.h>
#include <hip/hip_bf16.h>
#include <math.h>

#define N_DOC 4
#define C_    1024
#define D_    768
#define H_    12
#define E_    40
#define M_    3
#define P_    800
#define NP_   3200
#define EMB_  768
#define NREL_ 97
#define IN2_  1536   // 2*D
#define NPART 24     // 12 k-blocks x 2 b-halves

// ---------------------------------------------------------------- A: ent_emb
__global__ void k_ent_emb(const float* __restrict__ seq, const int* __restrict__ mpos,
                          float* __restrict__ ent_emb) {
  int ne = blockIdx.x;                 // 0..159
  int n = ne / E_, e = ne % E_;
  int base = (n * E_ + e) * M_;
  int p0 = mpos[base + 0] + 1, p1 = mpos[base + 1] + 1, p2 = mpos[base + 2] + 1;
  const float* s0 = seq + ((size_t)n * C_ + p0) * D_;
  const float* s1 = seq + ((size_t)n * C_ + p1) * D_;
  const float* s2 = seq + ((size_t)n * C_ + p2) * D_;
  float* out = ent_emb + (size_t)ne * D_;
  for (int d = threadIdx.x; d < D_; d += blockDim.x) {
    double a = s0[d], b = s1[d], c = s2[d];
    double mx = fmax(a, fmax(b, c));
    double s = exp(a - mx) + exp(b - mx) + exp(c - mx);
    out[d] = (float)(mx + log(s));
  }
}

// ---------------------------------------------------------------- B: ent_att
__global__ void k_ent_att(const float* __restrict__ att, const int* __restrict__ mpos,
                          float* __restrict__ ent_att) {
  int idx = blockIdx.x * 256 + threadIdx.x;        // exactly N*E*H*C = 1966080
  int c = idx & (C_ - 1);
  int h = (idx >> 10) % H_;
  int rem = idx / (C_ * H_);
  int e = rem % E_;
  int n = rem / E_;
  int base = (n * E_ + e) * M_;
  float acc = 0.f;
#pragma unroll
  for (int m = 0; m < M_; ++m) {
    int p = mpos[base + m] + 1;
    acc += att[(((size_t)n * H_ + h) * C_ + p) * C_ + c];
  }
  ent_att[idx] = acc / 3.0f;
}

// ---------------------------------------------------------------- C: ht_att
__global__ void k_ht_att(const float* __restrict__ ent_att, const int* __restrict__ hts,
                         float* __restrict__ ht) {
  int np = blockIdx.x;                 // 0..3199
  int n = np / P_;
  int hi = hts[np * 2 + 0], ti = hts[np * 2 + 1];
  const float* ea_h = ent_att + (size_t)(n * E_ + hi) * H_ * C_;
  const float* ea_t = ent_att + (size_t)(n * E_ + ti) * H_ * C_;
  float v[4];
  float local = 0.f;
#pragma unroll
  for (int i = 0; i < 4; ++i) {
    int c = threadIdx.x + 256 * i;
    float a = 0.f;
#pragma unroll
    for (int h = 0; h < H_; ++h)
      a += ea_h[h * C_ + c] * ea_t[h * C_ + c];
    a /= 12.0f;
    v[i] = a;
    local += a;
  }
  __shared__ float red[256];
  red[threadIdx.x] = local;
  __syncthreads();
  for (int s = 128; s > 0; s >>= 1) {
    if (threadIdx.x < s) red[threadIdx.x] += red[threadIdx.x + s];
    __syncthreads();
  }
  float S = red[0] + 1e-5f;
#pragma unroll
  for (int i = 0; i < 4; ++i) {
    int c = threadIdx.x + 256 * i;
    ht[(size_t)np * C_ + c] = v[i] / S;
  }
}

// ---------------------------------------------------------------- D: rs GEMM
__global__ void k_rs(const float* __restrict__ ht, const float* __restrict__ seq,
                     float* __restrict__ rs) {
  const int pt0 = blockIdx.x * 16;     // 200 tiles
  const int n = pt0 / P_;
  const int ot = threadIdx.x & 63;
  const int jt = threadIdx.x >> 6;     // 0..3
  const int o0 = blockIdx.y * 256 + ot;
  __shared__ float hlds[16 * 66];
  float a32[4][4];
  double a64[4][4];
#pragma unroll
  for (int q = 0; q < 4; ++q)
#pragma unroll
    for (int i = 0; i < 4; ++i) { a32[q][i] = 0.f; a64[q][i] = 0.0; }
  const float* seqn = seq + (size_t)n * C_ * D_;
  for (int c0 = 0; c0 < C_; c0 += 64) {
    for (int l = threadIdx.x; l < 1024; l += 256) {
      int j = l >> 6, cc = l & 63;
      hlds[j * 66 + cc] = ht[(size_t)(pt0 + j) * C_ + c0 + cc];
    }
    __syncthreads();
#pragma unroll 4
    for (int cc = 0; cc < 64; ++cc) {
      float sv[4];
#pragma unroll
      for (int i = 0; i < 4; ++i) sv[i] = seqn[(size_t)(c0 + cc) * D_ + o0 + 64 * i];
#pragma unroll
      for (int q = 0; q < 4; ++q) {
        float w = hlds[(jt * 4 + q) * 66 + cc];
#pragma unroll
        for (int i = 0; i < 4; ++i) a32[q][i] += w * sv[i];
      }
    }
#pragma unroll
    for (int q = 0; q < 4; ++q)
#pragma unroll
      for (int i = 0; i < 4; ++i) { a64[q][i] += (double)a32[q][i]; a32[q][i] = 0.f; }
    __syncthreads();
  }
#pragma unroll
  for (int q = 0; q < 4; ++q) {
    int p = pt0 + jt * 4 + q;
#pragma unroll
    for (int i = 0; i < 4; ++i)
      rs[(size_t)p * D_ + o0 + 64 * i] = (float)a64[q][i];
  }
}

// ---------------------------------------------------------------- E: zh / zt
__global__ void k_zht(const float* __restrict__ ent_emb, const float* __restrict__ rs,
                      const int* __restrict__ hts, const float* __restrict__ W,
                      const float* __restrict__ bias, float* __restrict__ out,
                      int which, int dbl_tanh) {
  const int pt0 = blockIdx.x * 16;
  const int n = pt0 / P_;
  const int ot = threadIdx.x & 63;
  const int jt = threadIdx.x >> 6;
  const int o0 = blockIdx.y * 256 + ot;
  __shared__ float xlds[16 * 66];
  __shared__ int sidx[16];
  if (threadIdx.x < 16) sidx[threadIdx.x] = hts[(pt0 + threadIdx.x) * 2 + which];
  float a32[4][4];
  double a64[4][4];
#pragma unroll
  for (int q = 0; q < 4; ++q)
#pragma unroll
    for (int i = 0; i < 4; ++i) { a32[q][i] = 0.f; a64[q][i] = 0.0; }
  __syncthreads();
  for (int k0 = 0; k0 < IN2_; k0 += 64) {
    for (int l = threadIdx.x; l < 1024; l += 256) {
      int j = l >> 6, q = l & 63;
      int kx = k0 + q;
      float val;
      if (kx < D_) val = ent_emb[(size_t)(n * E_ + sidx[j]) * D_ + kx];
      else         val = rs[(size_t)(pt0 + j) * D_ + (kx - D_)];
      xlds[j * 66 + q] = val;
    }
    __syncthreads();
#pragma unroll 4
    for (int q = 0; q < 64; ++q) {
      float wv[4];
#pragma unroll
      for (int i = 0; i < 4; ++i) wv[i] = W[(size_t)(k0 + q) * EMB_ + o0 + 64 * i];
#pragma unroll
      for (int j = 0; j < 4; ++j) {
        float x = xlds[(jt * 4 + j) * 66 + q];
#pragma unroll
        for (int i = 0; i < 4; ++i) a32[j][i] += x * wv[i];
      }
    }
#pragma unroll
    for (int j = 0; j < 4; ++j)
#pragma unroll
      for (int i = 0; i < 4; ++i) { a64[j][i] += (double)a32[j][i]; a32[j][i] = 0.f; }
    __syncthreads();
  }
#pragma unroll
  for (int j = 0; j < 4; ++j) {
    int p = pt0 + jt * 4 + j;
#pragma unroll
    for (int i = 0; i < 4; ++i) {
      int o = o0 + 64 * i;
      double z = a64[j][i] + (double)bias[o];
      z = tanh(z);
      if (dbl_tanh) z = tanh(z);
      out[(size_t)p * EMB_ + o] = (float)z;
    }
  }
}

// ---------------------------------------------------------------- F: logits partial
// part[(k*2+bh)][p,r] = sum_{b in half, c} zh[p,64k+b]*zt[p,64k+c]*Wb[(64k+b)*64+c, r]
// fp32 accumulation (partials are ~2048-term sums; f64 only in the final 24-way reduce)
__global__ __launch_bounds__(128) void k_logits_part(
    const float* __restrict__ zh, const float* __restrict__ zt,
    const float* __restrict__ Wb, float* __restrict__ part) {
  const int pt0 = blockIdx.x * 32;     // 100 pair tiles
  const int k  = blockIdx.y;           // 0..11
  const int bh = blockIdx.z;           // 0..1 -> b in [bh*32, bh*32+32)
  const int rt = threadIdx.x & 15;     // r = rt + 16*i (i<6), plus r=96 on rt==0
  const int jg = threadIdx.x >> 4;     // 0..7 -> pairs jg*4+q
  __shared__ float zh_t[32 * 34];
  __shared__ float zt_t[32 * 66];
  float acc[4][7];
#pragma unroll
  for (int q = 0; q < 4; ++q)
#pragma unroll
    for (int i = 0; i < 7; ++i) acc[q][i] = 0.f;

  for (int l = threadIdx.x; l < 1024; l += 128) {
    int j = l >> 5, b = l & 31;
    zh_t[j * 34 + b] = zh[(size_t)(pt0 + j) * EMB_ + k * 64 + bh * 32 + b];
  }
  for (int l = threadIdx.x; l < 2048; l += 128) {
    int j = l >> 6, c = l & 63;
    zt_t[j * 66 + c] = zt[(size_t)(pt0 + j) * EMB_ + k * 64 + c];
  }
  __syncthreads();

  for (int b = 0; b < 32; ++b) {
    float zhv[4];
#pragma unroll
    for (int q = 0; q < 4; ++q) zhv[q] = zh_t[(jg * 4 + q) * 34 + b];
    const float* wrow = Wb + (size_t)((k * 64 + bh * 32 + b) * 64) * NREL_;
#pragma unroll 2
    for (int c = 0; c < 64; ++c) {
      float w[6];
#pragma unroll
      for (int i = 0; i < 6; ++i) w[i] = wrow[c * NREL_ + rt + 16 * i];
      float w6 = (rt == 0) ? wrow[c * NREL_ + 96] : 0.f;
#pragma unroll
      for (int q = 0; q < 4; ++q) {
        float pz = zhv[q] * zt_t[(jg * 4 + q) * 66 + c];
#pragma unroll
        for (int i = 0; i < 6; ++i) acc[q][i] += pz * w[i];
        acc[q][6] += pz * w6;
      }
    }
  }
  float* po = part + (size_t)(k * 2 + bh) * NP_ * NREL_;
#pragma unroll
  for (int q = 0; q < 4; ++q) {
    int p = pt0 + jg * 4 + q;
#pragma unroll
    for (int i = 0; i < 6; ++i)
      po[(size_t)p * NREL_ + rt + 16 * i] = acc[q][i];
    if (rt == 0) po[(size_t)p * NREL_ + 96] = acc[q][6];
  }
}

// ---------------------------------------------------------------- G: finalize
__global__ void k_final(const float* __restrict__ part, const float* __restrict__ bb,
                        float* __restrict__ out) {
  const int p = blockIdx.x;
  const int r = threadIdx.x;           // 128 threads
  __shared__ double th_s;
  __shared__ int cnt[128];
  double v = 0.0;
  if (r < NREL_) {
#pragma unroll
    for (int g = 0; g < NPART; ++g)
      v += (double)part[(size_t)g * NP_ * NREL_ + (size_t)p * NREL_ + r];
    v += (double)bb[r];
    out[(size_t)p * NREL_ + r] = (float)v;
  }
  if (r == 0) th_s = v;
  __syncthreads();
  int pred = (r >= 1 && r < NREL_ && v > th_s) ? 1 : 0;
  cnt[r] = pred;
  __syncthreads();
  for (int s = 64; s > 0; s >>= 1) {
    if (r < s) cnt[r] += cnt[r + s];
    __syncthreads();
  }
  if (r < NREL_) {
    float pv = (r == 0) ? ((cnt[0] == 0) ? 1.f : 0.f) : (float)pred;
    out[(size_t)NP_ * NREL_ + (size_t)p * NREL_ + r] = pv;
  }
}

extern "C" void kernel_launch(void* const* d_in, const int* in_sizes, int n_in,
                              void* d_out, int out_size, void* d_ws, size_t ws_size,
                              hipStream_t stream) {
  const float* seq  = (const float*)d_in[0];
  const float* att  = (const float*)d_in[1];
  const int*   mpos = (const int*)d_in[2];
  const int*   hts  = (const int*)d_in[3];
  const float* Wh   = (const float*)d_in[4];
  const float* bh   = (const float*)d_in[5];
  const float* Wt   = (const float*)d_in[6];
  const float* bt   = (const float*)d_in[7];
  const float* Wb   = (const float*)d_in[8];
  const float* bb   = (const float*)d_in[9];
  float* out = (float*)d_out;
  float* ws = (float*)d_ws;

  float* ent_emb = ws;                   // [0, 122880)
  float* ent_att = ws + 122880;          // [122880, 2088960)   dead after k_ht_att
  float* ht      = ws + 2088960;         // [2088960, 5365760)  dead after k_rs
  float* rs      = ws + 5365760;         // [5365760, 7823360)  dead after k_zht
  float* zh      = ws + 7823360;         // [7823360, 10280960)
  float* zt      = ws + 10280960;        // [10280960, 12738560)
  // part (24*3200*97 = 7,449,600 floats) aliases the dead ent_att+ht+rs region:
  // [122880, 7572480) < 7823360 -- written by k_logits_part after rs is dead.
  float* part    = ws + 122880;

  k_ent_emb<<<160, 256, 0, stream>>>(seq, mpos, ent_emb);
  k_ent_att<<<7680, 256, 0, stream>>>(att, mpos, ent_att);
  k_ht_att<<<3200, 256, 0, stream>>>(ent_att, hts, ht);
  k_rs<<<dim3(200, 3), 256, 0, stream>>>(ht, seq, rs);
  k_zht<<<dim3(200, 3), 256, 0, stream>>>(ent_emb, rs, hts, Wh, bh, zh, 0, 1);
  k_zht<<<dim3(200, 3), 256, 0, stream>>>(ent_emb, rs, hts, Wt, bt, zt, 1, 0);
  k_logits_part<<<dim3(100, 12, 2), 128, 0, stream>>>(zh, zt, Wb, part);
  k_final<<<3200, 128, 0, stream>>>(part, bb, out);
}

// Round 3
// 1423.553 us; speedup vs baseline: 3.0126x; 1.0163x over previous
//
#include <hip/hip_runtime.h>
#include <hip/hip_bf16.h>
#include <math.h>

#define N_DOC 4
#define C_    1024
#define D_    768
#define H_    12
#define E_    40
#define M_    3
#define P_    800
#define NP_   3200
#define EMB_  768
#define NREL_ 97
#define IN2_  1536   // 2*D
#define NPART 24     // 12 k-blocks x 2 b-halves

// ---------------------------------------------------------------- A: ent_emb
__global__ void k_ent_emb(const float* __restrict__ seq, const int* __restrict__ mpos,
                          float* __restrict__ ent_emb) {
  int ne = blockIdx.x;                 // 0..159
  int n = ne / E_, e = ne % E_;
  int base = (n * E_ + e) * M_;
  int p0 = mpos[base + 0] + 1, p1 = mpos[base + 1] + 1, p2 = mpos[base + 2] + 1;
  const float* s0 = seq + ((size_t)n * C_ + p0) * D_;
  const float* s1 = seq + ((size_t)n * C_ + p1) * D_;
  const float* s2 = seq + ((size_t)n * C_ + p2) * D_;
  float* out = ent_emb + (size_t)ne * D_;
  for (int d = threadIdx.x; d < D_; d += blockDim.x) {
    double a = s0[d], b = s1[d], c = s2[d];
    double mx = fmax(a, fmax(b, c));
    double s = exp(a - mx) + exp(b - mx) + exp(c - mx);
    out[d] = (float)(mx + log(s));
  }
}

// ---------------------------------------------------------------- B: ent_att
__global__ void k_ent_att(const float* __restrict__ att, const int* __restrict__ mpos,
                          float* __restrict__ ent_att) {
  int idx = blockIdx.x * 256 + threadIdx.x;        // exactly N*E*H*C = 1966080
  int c = idx & (C_ - 1);
  int h = (idx >> 10) % H_;
  int rem = idx / (C_ * H_);
  int e = rem % E_;
  int n = rem / E_;
  int base = (n * E_ + e) * M_;
  float acc = 0.f;
#pragma unroll
  for (int m = 0; m < M_; ++m) {
    int p = mpos[base + m] + 1;
    acc += att[(((size_t)n * H_ + h) * C_ + p) * C_ + c];
  }
  ent_att[idx] = acc / 3.0f;
}

// ---------------------------------------------------------------- C: ht_att
__global__ void k_ht_att(const float* __restrict__ ent_att, const int* __restrict__ hts,
                         float* __restrict__ ht) {
  int np = blockIdx.x;                 // 0..3199
  int n = np / P_;
  int hi = hts[np * 2 + 0], ti = hts[np * 2 + 1];
  const float* ea_h = ent_att + (size_t)(n * E_ + hi) * H_ * C_;
  const float* ea_t = ent_att + (size_t)(n * E_ + ti) * H_ * C_;
  float v[4];
  float local = 0.f;
#pragma unroll
  for (int i = 0; i < 4; ++i) {
    int c = threadIdx.x + 256 * i;
    float a = 0.f;
#pragma unroll
    for (int h = 0; h < H_; ++h)
      a += ea_h[h * C_ + c] * ea_t[h * C_ + c];
    a /= 12.0f;
    v[i] = a;
    local += a;
  }
  __shared__ float red[256];
  red[threadIdx.x] = local;
  __syncthreads();
  for (int s = 128; s > 0; s >>= 1) {
    if (threadIdx.x < s) red[threadIdx.x] += red[threadIdx.x + s];
    __syncthreads();
  }
  float S = red[0] + 1e-5f;
#pragma unroll
  for (int i = 0; i < 4; ++i) {
    int c = threadIdx.x + 256 * i;
    ht[(size_t)np * C_ + c] = v[i] / S;
  }
}

// ---------------------------------------------------------------- D: rs GEMM
__global__ void k_rs(const float* __restrict__ ht, const float* __restrict__ seq,
                     float* __restrict__ rs) {
  const int pt0 = blockIdx.x * 16;     // 200 tiles
  const int n = pt0 / P_;
  const int ot = threadIdx.x & 63;
  const int jt = threadIdx.x >> 6;     // 0..3
  const int o0 = blockIdx.y * 256 + ot;
  __shared__ float hlds[16 * 66];
  float a32[4][4];
  double a64[4][4];
#pragma unroll
  for (int q = 0; q < 4; ++q)
#pragma unroll
    for (int i = 0; i < 4; ++i) { a32[q][i] = 0.f; a64[q][i] = 0.0; }
  const float* seqn = seq + (size_t)n * C_ * D_;
  for (int c0 = 0; c0 < C_; c0 += 64) {
    for (int l = threadIdx.x; l < 1024; l += 256) {
      int j = l >> 6, cc = l & 63;
      hlds[j * 66 + cc] = ht[(size_t)(pt0 + j) * C_ + c0 + cc];
    }
    __syncthreads();
#pragma unroll 4
    for (int cc = 0; cc < 64; ++cc) {
      float sv[4];
#pragma unroll
      for (int i = 0; i < 4; ++i) sv[i] = seqn[(size_t)(c0 + cc) * D_ + o0 + 64 * i];
#pragma unroll
      for (int q = 0; q < 4; ++q) {
        float w = hlds[(jt * 4 + q) * 66 + cc];
#pragma unroll
        for (int i = 0; i < 4; ++i) a32[q][i] += w * sv[i];
      }
    }
#pragma unroll
    for (int q = 0; q < 4; ++q)
#pragma unroll
      for (int i = 0; i < 4; ++i) { a64[q][i] += (double)a32[q][i]; a32[q][i] = 0.f; }
    __syncthreads();
  }
#pragma unroll
  for (int q = 0; q < 4; ++q) {
    int p = pt0 + jt * 4 + q;
#pragma unroll
    for (int i = 0; i < 4; ++i)
      rs[(size_t)p * D_ + o0 + 64 * i] = (float)a64[q][i];
  }
}

// ---------------------------------------------------------------- E: zh / zt
__global__ void k_zht(const float* __restrict__ ent_emb, const float* __restrict__ rs,
                      const int* __restrict__ hts, const float* __restrict__ W,
                      const float* __restrict__ bias, float* __restrict__ out,
                      int which, int dbl_tanh) {
  const int pt0 = blockIdx.x * 16;
  const int n = pt0 / P_;
  const int ot = threadIdx.x & 63;
  const int jt = threadIdx.x >> 6;
  const int o0 = blockIdx.y * 256 + ot;
  __shared__ float xlds[16 * 66];
  __shared__ int sidx[16];
  if (threadIdx.x < 16) sidx[threadIdx.x] = hts[(pt0 + threadIdx.x) * 2 + which];
  float a32[4][4];
  double a64[4][4];
#pragma unroll
  for (int q = 0; q < 4; ++q)
#pragma unroll
    for (int i = 0; i < 4; ++i) { a32[q][i] = 0.f; a64[q][i] = 0.0; }
  __syncthreads();
  for (int k0 = 0; k0 < IN2_; k0 += 64) {
    for (int l = threadIdx.x; l < 1024; l += 256) {
      int j = l >> 6, q = l & 63;
      int kx = k0 + q;
      float val;
      if (kx < D_) val = ent_emb[(size_t)(n * E_ + sidx[j]) * D_ + kx];
      else         val = rs[(size_t)(pt0 + j) * D_ + (kx - D_)];
      xlds[j * 66 + q] = val;
    }
    __syncthreads();
#pragma unroll 4
    for (int q = 0; q < 64; ++q) {
      float wv[4];
#pragma unroll
      for (int i = 0; i < 4; ++i) wv[i] = W[(size_t)(k0 + q) * EMB_ + o0 + 64 * i];
#pragma unroll
      for (int j = 0; j < 4; ++j) {
        float x = xlds[(jt * 4 + j) * 66 + q];
#pragma unroll
        for (int i = 0; i < 4; ++i) a32[j][i] += x * wv[i];
      }
    }
#pragma unroll
    for (int j = 0; j < 4; ++j)
#pragma unroll
      for (int i = 0; i < 4; ++i) { a64[j][i] += (double)a32[j][i]; a32[j][i] = 0.f; }
    __syncthreads();
  }
#pragma unroll
  for (int j = 0; j < 4; ++j) {
    int p = pt0 + jt * 4 + j;
#pragma unroll
    for (int i = 0; i < 4; ++i) {
      int o = o0 + 64 * i;
      double z = a64[j][i] + (double)bias[o];
      z = tanh(z);
      if (dbl_tanh) z = tanh(z);
      out[(size_t)p * EMB_ + o] = (float)z;
    }
  }
}

// ---------------------------------------------------------------- F: logits partial (r 0..95)
// part[(k*2+bh)][p][r] = sum_{b in bh-half, c} zh[p,64k+b]*zt[p,64k+c]*Wb[((64k+b)*64+c), r]
// Register-tiled: thread = (rt 0..15, pg 0..7); 8 pairs x 6 r-slots per thread.
// Wb b-slice (64 c-rows x 97 r) transposed into LDS as W_t[r][c] so W reads are
// float4-over-c ds_read_b128 (conflict-free: row stride 68 dwords).
__global__ __launch_bounds__(128, 3) void k_logits_part(
    const float* __restrict__ zh, const float* __restrict__ zt,
    const float* __restrict__ Wb, float* __restrict__ part) {
  const int pt0 = blockIdx.x * 64;     // 50 pair tiles
  const int k  = blockIdx.y;           // 0..11
  const int bh = blockIdx.z;           // 0..1
  const int rt = threadIdx.x & 15;
  const int pg = threadIdx.x >> 4;     // 0..7 -> pairs pg*8+j
  __shared__ float Wt[97 * 68];
  float acc[8][6];
#pragma unroll
  for (int j = 0; j < 8; ++j)
#pragma unroll
    for (int i = 0; i < 6; ++i) acc[j][i] = 0.f;

  const int kb0 = k * 64 + bh * 32;
  const float* ztb = zt + (size_t)pt0 * EMB_ + k * 64;   // per-pair rows, stride EMB_

  for (int b = 0; b < 32; ++b) {
    __syncthreads();
    // ---- stage transposed W slice: Wb rows [(kb0+b)*64 .. +64) x 97 -> Wt[r][c]
    {
      const float4* src = (const float4*)(Wb + (size_t)(kb0 + b) * 6208); // 64*97, 16B-aligned
      for (int u = threadIdx.x; u < 1552; u += 128) {
        float4 v = src[u];
        float ve[4] = {v.x, v.y, v.z, v.w};
        int idx = u * 4;
#pragma unroll
        for (int e = 0; e < 4; ++e) {
          int t = idx + e;
          int c = t / 97;            // magic-mul div (constant)
          int r = t - c * 97;
          Wt[r * 68 + c] = ve[e];
        }
      }
    }
    __syncthreads();
    float zhb[8];
#pragma unroll
    for (int j = 0; j < 8; ++j)
      zhb[j] = zh[(size_t)(pt0 + pg * 8 + j) * EMB_ + kb0 + b];
    for (int c0 = 0; c0 < 64; c0 += 4) {
      float4 pz[8];
#pragma unroll
      for (int j = 0; j < 8; ++j) {
        float4 z = *(const float4*)(ztb + (size_t)(pg * 8 + j) * EMB_ + c0);
        pz[j].x = zhb[j] * z.x; pz[j].y = zhb[j] * z.y;
        pz[j].z = zhb[j] * z.z; pz[j].w = zhb[j] * z.w;
      }
#pragma unroll
      for (int i = 0; i < 6; ++i) {
        float4 w = *(const float4*)&Wt[(rt + 16 * i) * 68 + c0];
#pragma unroll
        for (int j = 0; j < 8; ++j) {
          acc[j][i] += pz[j].x * w.x;
          acc[j][i] += pz[j].y * w.y;
          acc[j][i] += pz[j].z * w.z;
          acc[j][i] += pz[j].w * w.w;
        }
      }
    }
  }
  float* po = part + (size_t)(k * 2 + bh) * NP_ * NREL_;
#pragma unroll
  for (int j = 0; j < 8; ++j) {
    int p = pt0 + pg * 8 + j;
#pragma unroll
    for (int i = 0; i < 6; ++i)
      po[(size_t)p * NREL_ + rt + 16 * i] = acc[j][i];
  }
}

// ---------------------------------------------------------------- F2: r=96 column
// part[(k*2+bh)][p][96] = sum_{b,c} zh[p,64k+bh*32+b]*zt[p,64k+c]*Wb[row][96]
__global__ void k_r96(const float* __restrict__ zh, const float* __restrict__ zt,
                      const float* __restrict__ Wb, float* __restrict__ part) {
  const int pt0 = blockIdx.x * 64;
  const int k  = blockIdx.y;
  const int bh = blockIdx.z;
  const int p = pt0 + (threadIdx.x >> 1);   // 128 thr: pair = tid>>1
  const int ch = threadIdx.x & 1;           // c-half
  const int kb0 = k * 64 + bh * 32;
  const float* zhr = zh + (size_t)p * EMB_ + kb0;
  const float* ztr = zt + (size_t)p * EMB_ + k * 64 + ch * 32;
  float acc = 0.f;
  for (int b = 0; b < 32; ++b) {
    float zhb = zhr[b];
    const float* w = Wb + (size_t)((kb0 + b) * 64 + ch * 32) * NREL_ + 96;
#pragma unroll 8
    for (int c = 0; c < 32; ++c)
      acc += zhb * ztr[c] * w[(size_t)c * NREL_];
  }
  acc += __shfl_xor(acc, 1);
  if (ch == 0)
    part[(size_t)(k * 2 + bh) * NP_ * NREL_ + (size_t)p * NREL_ + 96] = acc;
}

// ---------------------------------------------------------------- G: finalize
__global__ void k_final(const float* __restrict__ part, const float* __restrict__ bb,
                        float* __restrict__ out) {
  const int p = blockIdx.x;
  const int r = threadIdx.x;           // 128 threads
  __shared__ double th_s;
  __shared__ int cnt[128];
  double v = 0.0;
  if (r < NREL_) {
#pragma unroll
    for (int g = 0; g < NPART; ++g)
      v += (double)part[(size_t)g * NP_ * NREL_ + (size_t)p * NREL_ + r];
    v += (double)bb[r];
    out[(size_t)p * NREL_ + r] = (float)v;
  }
  if (r == 0) th_s = v;
  __syncthreads();
  int pred = (r >= 1 && r < NREL_ && v > th_s) ? 1 : 0;
  cnt[r] = pred;
  __syncthreads();
  for (int s = 64; s > 0; s >>= 1) {
    if (r < s) cnt[r] += cnt[r + s];
    __syncthreads();
  }
  if (r < NREL_) {
    float pv = (r == 0) ? ((cnt[0] == 0) ? 1.f : 0.f) : (float)pred;
    out[(size_t)NP_ * NREL_ + (size_t)p * NREL_ + r] = pv;
  }
}

extern "C" void kernel_launch(void* const* d_in, const int* in_sizes, int n_in,
                              void* d_out, int out_size, void* d_ws, size_t ws_size,
                              hipStream_t stream) {
  const float* seq  = (const float*)d_in[0];
  const float* att  = (const float*)d_in[1];
  const int*   mpos = (const int*)d_in[2];
  const int*   hts  = (const int*)d_in[3];
  const float* Wh   = (const float*)d_in[4];
  const float* bh   = (const float*)d_in[5];
  const float* Wt   = (const float*)d_in[6];
  const float* bt   = (const float*)d_in[7];
  const float* Wb   = (const float*)d_in[8];
  const float* bb   = (const float*)d_in[9];
  float* out = (float*)d_out;
  float* ws = (float*)d_ws;

  float* ent_emb = ws;                   // [0, 122880)
  float* ent_att = ws + 122880;          // [122880, 2088960)   dead after k_ht_att
  float* ht      = ws + 2088960;         // [2088960, 5365760)  dead after k_rs
  float* rs      = ws + 5365760;         // [5365760, 7823360)  dead after k_zht
  float* zh      = ws + 7823360;         // [7823360, 10280960)
  float* zt      = ws + 10280960;        // [10280960, 12738560)
  // part (24*3200*97 = 7,449,600 floats) aliases the dead ent_att+ht+rs region:
  // [122880, 7572480) < 7823360 -- written after rs is dead.
  float* part    = ws + 122880;

  k_ent_emb<<<160, 256, 0, stream>>>(seq, mpos, ent_emb);
  k_ent_att<<<7680, 256, 0, stream>>>(att, mpos, ent_att);
  k_ht_att<<<3200, 256, 0, stream>>>(ent_att, hts, ht);
  k_rs<<<dim3(200, 3), 256, 0, stream>>>(ht, seq, rs);
  k_zht<<<dim3(200, 3), 256, 0, stream>>>(ent_emb, rs, hts, Wh, bh, zh, 0, 1);
  k_zht<<<dim3(200, 3), 256, 0, stream>>>(ent_emb, rs, hts, Wt, bt, zt, 1, 0);
  k_logits_part<<<dim3(50, 12, 2), 128, 0, stream>>>(zh, zt, Wb, part);
  k_r96<<<dim3(50, 12, 2), 128, 0, stream>>>(zh, zt, Wb, part);
  k_final<<<3200, 128, 0, stream>>>(part, bb, out);
}

// Round 4
// 1344.410 us; speedup vs baseline: 3.1900x; 1.0589x over previous
//
#include <hip/hip_runtime.h>
#include <hip/hip_bf16.h>
#include <math.h>

#define N_DOC 4
#define C_    1024
#define D_    768
#define H_    12
#define E_    40
#define M_    3
#define P_    800
#define NP_   3200
#define EMB_  768
#define NREL_ 97
#define IN2_  1536   // 2*D
#define NPART 24     // 12 k-blocks x 2 b-halves

// ---------------------------------------------------------------- A: ent_emb
__global__ void k_ent_emb(const float* __restrict__ seq, const int* __restrict__ mpos,
                          float* __restrict__ ent_emb) {
  int ne = blockIdx.x;                 // 0..159
  int n = ne / E_, e = ne % E_;
  int base = (n * E_ + e) * M_;
  int p0 = mpos[base + 0] + 1, p1 = mpos[base + 1] + 1, p2 = mpos[base + 2] + 1;
  const float* s0 = seq + ((size_t)n * C_ + p0) * D_;
  const float* s1 = seq + ((size_t)n * C_ + p1) * D_;
  const float* s2 = seq + ((size_t)n * C_ + p2) * D_;
  float* out = ent_emb + (size_t)ne * D_;
  for (int d = threadIdx.x; d < D_; d += blockDim.x) {
    double a = s0[d], b = s1[d], c = s2[d];
    double mx = fmax(a, fmax(b, c));
    double s = exp(a - mx) + exp(b - mx) + exp(c - mx);
    out[d] = (float)(mx + log(s));
  }
}

// ---------------------------------------------------------------- B: ent_att
__global__ void k_ent_att(const float* __restrict__ att, const int* __restrict__ mpos,
                          float* __restrict__ ent_att) {
  int idx = blockIdx.x * 256 + threadIdx.x;        // exactly N*E*H*C = 1966080
  int c = idx & (C_ - 1);
  int h = (idx >> 10) % H_;
  int rem = idx / (C_ * H_);
  int e = rem % E_;
  int n = rem / E_;
  int base = (n * E_ + e) * M_;
  float acc = 0.f;
#pragma unroll
  for (int m = 0; m < M_; ++m) {
    int p = mpos[base + m] + 1;
    acc += att[(((size_t)n * H_ + h) * C_ + p) * C_ + c];
  }
  ent_att[idx] = acc / 3.0f;
}

// ---------------------------------------------------------------- C: ht_att
__global__ void k_ht_att(const float* __restrict__ ent_att, const int* __restrict__ hts,
                         float* __restrict__ ht) {
  int np = blockIdx.x;                 // 0..3199
  int n = np / P_;
  int hi = hts[np * 2 + 0], ti = hts[np * 2 + 1];
  const float* ea_h = ent_att + (size_t)(n * E_ + hi) * H_ * C_;
  const float* ea_t = ent_att + (size_t)(n * E_ + ti) * H_ * C_;
  float v[4];
  float local = 0.f;
#pragma unroll
  for (int i = 0; i < 4; ++i) {
    int c = threadIdx.x + 256 * i;
    float a = 0.f;
#pragma unroll
    for (int h = 0; h < H_; ++h)
      a += ea_h[h * C_ + c] * ea_t[h * C_ + c];
    a /= 12.0f;
    v[i] = a;
    local += a;
  }
  __shared__ float red[256];
  red[threadIdx.x] = local;
  __syncthreads();
  for (int s = 128; s > 0; s >>= 1) {
    if (threadIdx.x < s) red[threadIdx.x] += red[threadIdx.x + s];
    __syncthreads();
  }
  float S = red[0] + 1e-5f;
#pragma unroll
  for (int i = 0; i < 4; ++i) {
    int c = threadIdx.x + 256 * i;
    ht[(size_t)np * C_ + c] = v[i] / S;
  }
}

// ---------------------------------------------------------------- D: rs GEMM
__global__ void k_rs(const float* __restrict__ ht, const float* __restrict__ seq,
                     float* __restrict__ rs) {
  const int pt0 = blockIdx.x * 16;     // 200 tiles
  const int n = pt0 / P_;
  const int ot = threadIdx.x & 63;
  const int jt = threadIdx.x >> 6;     // 0..3
  const int o0 = blockIdx.y * 256 + ot;
  __shared__ float hlds[16 * 66];
  float a32[4][4];
  double a64[4][4];
#pragma unroll
  for (int q = 0; q < 4; ++q)
#pragma unroll
    for (int i = 0; i < 4; ++i) { a32[q][i] = 0.f; a64[q][i] = 0.0; }
  const float* seqn = seq + (size_t)n * C_ * D_;
  for (int c0 = 0; c0 < C_; c0 += 64) {
    for (int l = threadIdx.x; l < 1024; l += 256) {
      int j = l >> 6, cc = l & 63;
      hlds[j * 66 + cc] = ht[(size_t)(pt0 + j) * C_ + c0 + cc];
    }
    __syncthreads();
#pragma unroll 4
    for (int cc = 0; cc < 64; ++cc) {
      float sv[4];
#pragma unroll
      for (int i = 0; i < 4; ++i) sv[i] = seqn[(size_t)(c0 + cc) * D_ + o0 + 64 * i];
#pragma unroll
      for (int q = 0; q < 4; ++q) {
        float w = hlds[(jt * 4 + q) * 66 + cc];
#pragma unroll
        for (int i = 0; i < 4; ++i) a32[q][i] += w * sv[i];
      }
    }
#pragma unroll
    for (int q = 0; q < 4; ++q)
#pragma unroll
      for (int i = 0; i < 4; ++i) { a64[q][i] += (double)a32[q][i]; a32[q][i] = 0.f; }
    __syncthreads();
  }
#pragma unroll
  for (int q = 0; q < 4; ++q) {
    int p = pt0 + jt * 4 + q;
#pragma unroll
    for (int i = 0; i < 4; ++i)
      rs[(size_t)p * D_ + o0 + 64 * i] = (float)a64[q][i];
  }
}

// ---------------------------------------------------------------- E: zh / zt
__global__ void k_zht(const float* __restrict__ ent_emb, const float* __restrict__ rs,
                      const int* __restrict__ hts, const float* __restrict__ W,
                      const float* __restrict__ bias, float* __restrict__ out,
                      int which, int dbl_tanh) {
  const int pt0 = blockIdx.x * 16;
  const int n = pt0 / P_;
  const int ot = threadIdx.x & 63;
  const int jt = threadIdx.x >> 6;
  const int o0 = blockIdx.y * 256 + ot;
  __shared__ float xlds[16 * 66];
  __shared__ int sidx[16];
  if (threadIdx.x < 16) sidx[threadIdx.x] = hts[(pt0 + threadIdx.x) * 2 + which];
  float a32[4][4];
  double a64[4][4];
#pragma unroll
  for (int q = 0; q < 4; ++q)
#pragma unroll
    for (int i = 0; i < 4; ++i) { a32[q][i] = 0.f; a64[q][i] = 0.0; }
  __syncthreads();
  for (int k0 = 0; k0 < IN2_; k0 += 64) {
    for (int l = threadIdx.x; l < 1024; l += 256) {
      int j = l >> 6, q = l & 63;
      int kx = k0 + q;
      float val;
      if (kx < D_) val = ent_emb[(size_t)(n * E_ + sidx[j]) * D_ + kx];
      else         val = rs[(size_t)(pt0 + j) * D_ + (kx - D_)];
      xlds[j * 66 + q] = val;
    }
    __syncthreads();
#pragma unroll 4
    for (int q = 0; q < 64; ++q) {
      float wv[4];
#pragma unroll
      for (int i = 0; i < 4; ++i) wv[i] = W[(size_t)(k0 + q) * EMB_ + o0 + 64 * i];
#pragma unroll
      for (int j = 0; j < 4; ++j) {
        float x = xlds[(jt * 4 + j) * 66 + q];
#pragma unroll
        for (int i = 0; i < 4; ++i) a32[j][i] += x * wv[i];
      }
    }
#pragma unroll
    for (int j = 0; j < 4; ++j)
#pragma unroll
      for (int i = 0; i < 4; ++i) { a64[j][i] += (double)a32[j][i]; a32[j][i] = 0.f; }
    __syncthreads();
  }
#pragma unroll
  for (int j = 0; j < 4; ++j) {
    int p = pt0 + jt * 4 + j;
#pragma unroll
    for (int i = 0; i < 4; ++i) {
      int o = o0 + 64 * i;
      double z = a64[j][i] + (double)bias[o];
      z = tanh(z);
      if (dbl_tanh) z = tanh(z);
      out[(size_t)p * EMB_ + o] = (float)z;
    }
  }
}

// ---------------------------------------------------------------- F: logits partial (r 0..95)
// part[(k*2+bh)][p][r] = sum_{b in bh-half, c} zh[p,64k+b]*zt[p,64k+c]*Wb[((64k+b)*64+c), r]
// Linear LDS staging of the 64x97 Wb slice (no transpose, conflict-free b128
// copy); compute reads w as scalar LDS broadcasts (16 consecutive addrs x 4-way
// broadcast = conflict-free). Block swizzle: bid = s + 24*t puts all 50 p-tiles
// of slab s=(k,bh) on XCD s%8 (24*t = 0 mod 8) -> slab stays L2-resident.
__global__ __launch_bounds__(128) void k_logits_part(
    const float* __restrict__ zh, const float* __restrict__ zt,
    const float* __restrict__ Wb, float* __restrict__ part) {
  const int bid = blockIdx.x;          // 0..1199
  const int s   = bid % 24;            // slab = k*2+bh
  const int t   = bid / 24;            // p-tile 0..49
  const int k   = s >> 1, bh = s & 1;
  const int pt0 = t * 64;
  const int rt = threadIdx.x & 15;
  const int pg = threadIdx.x >> 4;     // 0..7 -> pairs pg*8+j
  __shared__ float Wlin[64 * 97];      // 24.25 KB, rows of 97 over c
  float acc[8][6];
#pragma unroll
  for (int j = 0; j < 8; ++j)
#pragma unroll
    for (int i = 0; i < 6; ++i) acc[j][i] = 0.f;

  const int kb0 = k * 64 + bh * 32;
  const float* ztb   = zt + (size_t)(pt0 + pg * 8) * EMB_ + k * 64;
  const float* zhb_g = zh + (size_t)(pt0 + pg * 8) * EMB_ + kb0;

  for (int b = 0; b < 32; ++b) {
    __syncthreads();                   // Wlin reuse guard
    {
      const float4* src = (const float4*)(Wb + (size_t)(kb0 + b) * 6208); // 64*97
      float4* dst = (float4*)Wlin;
#pragma unroll
      for (int u = 0; u < 12; ++u)
        dst[threadIdx.x + 128 * u] = src[threadIdx.x + 128 * u];   // 1536
      if (threadIdx.x < 16)
        dst[1536 + threadIdx.x] = src[1536 + threadIdx.x];         // 1552 total
    }
    __syncthreads();
    float zhv[8];
#pragma unroll
    for (int j = 0; j < 8; ++j) zhv[j] = zhb_g[(size_t)j * EMB_ + b];
    for (int c0 = 0; c0 < 64; c0 += 4) {
      float4 pz[8];
#pragma unroll
      for (int j = 0; j < 8; ++j) {
        float4 z = *(const float4*)(ztb + (size_t)j * EMB_ + c0);
        pz[j].x = zhv[j] * z.x; pz[j].y = zhv[j] * z.y;
        pz[j].z = zhv[j] * z.z; pz[j].w = zhv[j] * z.w;
      }
#pragma unroll
      for (int cc = 0; cc < 4; ++cc) {
        const float* wr = &Wlin[(c0 + cc) * 97];
        float pzc[8];
#pragma unroll
        for (int j = 0; j < 8; ++j)
          pzc[j] = (cc == 0) ? pz[j].x : (cc == 1) ? pz[j].y : (cc == 2) ? pz[j].z : pz[j].w;
#pragma unroll
        for (int i = 0; i < 6; ++i) {
          float w = wr[rt + 16 * i];
#pragma unroll
          for (int j = 0; j < 8; ++j)
            acc[j][i] += pzc[j] * w;
        }
      }
    }
  }
  float* po = part + (size_t)s * NP_ * NREL_;
#pragma unroll
  for (int j = 0; j < 8; ++j) {
    int p = pt0 + pg * 8 + j;
#pragma unroll
    for (int i = 0; i < 6; ++i)
      po[(size_t)p * NREL_ + rt + 16 * i] = acc[j][i];
  }
}

// ---------------------------------------------------------------- F2: r=96 column
__global__ void k_r96(const float* __restrict__ zh, const float* __restrict__ zt,
                      const float* __restrict__ Wb, float* __restrict__ part) {
  const int pt0 = blockIdx.x * 64;
  const int k  = blockIdx.y;
  const int bh = blockIdx.z;
  const int p = pt0 + (threadIdx.x >> 1);   // 128 thr: pair = tid>>1
  const int ch = threadIdx.x & 1;           // c-half
  const int kb0 = k * 64 + bh * 32;
  const float* zhr = zh + (size_t)p * EMB_ + kb0;
  const float* ztr = zt + (size_t)p * EMB_ + k * 64 + ch * 32;
  float acc = 0.f;
  for (int b = 0; b < 32; ++b) {
    float zhb = zhr[b];
    const float* w = Wb + (size_t)((kb0 + b) * 64 + ch * 32) * NREL_ + 96;
#pragma unroll 8
    for (int c = 0; c < 32; ++c)
      acc += zhb * ztr[c] * w[(size_t)c * NREL_];
  }
  acc += __shfl_xor(acc, 1);
  if (ch == 0)
    part[(size_t)(k * 2 + bh) * NP_ * NREL_ + (size_t)p * NREL_ + 96] = acc;
}

// ---------------------------------------------------------------- G: finalize
__global__ void k_final(const float* __restrict__ part, const float* __restrict__ bb,
                        float* __restrict__ out) {
  const int p = blockIdx.x;
  const int r = threadIdx.x;           // 128 threads
  __shared__ double th_s;
  __shared__ int cnt[128];
  double v = 0.0;
  if (r < NREL_) {
#pragma unroll
    for (int g = 0; g < NPART; ++g)
      v += (double)part[(size_t)g * NP_ * NREL_ + (size_t)p * NREL_ + r];
    v += (double)bb[r];
    out[(size_t)p * NREL_ + r] = (float)v;
  }
  if (r == 0) th_s = v;
  __syncthreads();
  int pred = (r >= 1 && r < NREL_ && v > th_s) ? 1 : 0;
  cnt[r] = pred;
  __syncthreads();
  for (int s = 64; s > 0; s >>= 1) {
    if (r < s) cnt[r] += cnt[r + s];
    __syncthreads();
  }
  if (r < NREL_) {
    float pv = (r == 0) ? ((cnt[0] == 0) ? 1.f : 0.f) : (float)pred;
    out[(size_t)NP_ * NREL_ + (size_t)p * NREL_ + r] = pv;
  }
}

extern "C" void kernel_launch(void* const* d_in, const int* in_sizes, int n_in,
                              void* d_out, int out_size, void* d_ws, size_t ws_size,
                              hipStream_t stream) {
  const float* seq  = (const float*)d_in[0];
  const float* att  = (const float*)d_in[1];
  const int*   mpos = (const int*)d_in[2];
  const int*   hts  = (const int*)d_in[3];
  const float* Wh   = (const float*)d_in[4];
  const float* bh   = (const float*)d_in[5];
  const float* Wt   = (const float*)d_in[6];
  const float* bt   = (const float*)d_in[7];
  const float* Wb   = (const float*)d_in[8];
  const float* bb   = (const float*)d_in[9];
  float* out = (float*)d_out;
  float* ws = (float*)d_ws;

  float* ent_emb = ws;                   // [0, 122880)
  float* ent_att = ws + 122880;          // [122880, 2088960)   dead after k_ht_att
  float* ht      = ws + 2088960;         // [2088960, 5365760)  dead after k_rs
  float* rs      = ws + 5365760;         // [5365760, 7823360)  dead after k_zht
  float* zh      = ws + 7823360;         // [7823360, 10280960)
  float* zt      = ws + 10280960;        // [10280960, 12738560)
  // part (24*3200*97 = 7,449,600 floats) aliases the dead ent_att+ht+rs region:
  // [122880, 7572480) < 7823360 -- written after rs is dead.
  float* part    = ws + 122880;

  k_ent_emb<<<160, 256, 0, stream>>>(seq, mpos, ent_emb);
  k_ent_att<<<7680, 256, 0, stream>>>(att, mpos, ent_att);
  k_ht_att<<<3200, 256, 0, stream>>>(ent_att, hts, ht);
  k_rs<<<dim3(200, 3), 256, 0, stream>>>(ht, seq, rs);
  k_zht<<<dim3(200, 3), 256, 0, stream>>>(ent_emb, rs, hts, Wh, bh, zh, 0, 1);
  k_zht<<<dim3(200, 3), 256, 0, stream>>>(ent_emb, rs, hts, Wt, bt, zt, 1, 0);
  k_logits_part<<<1200, 128, 0, stream>>>(zh, zt, Wb, part);
  k_r96<<<dim3(50, 12, 2), 128, 0, stream>>>(zh, zt, Wb, part);
  k_final<<<3200, 128, 0, stream>>>(part, bb, out);
}